// Round 4
// baseline (392.488 us; speedup 1.0000x reference)
//
#include <hip/hip_runtime.h>
#include <hip/hip_bf16.h>

#define BB 16
#define TT 2048
#define VV 512

typedef __attribute__((ext_vector_type(8))) short short8;
typedef __attribute__((ext_vector_type(4))) float floatx4;

static __device__ inline ushort f2bf(float f) {
  __hip_bfloat16 h = __float2bfloat16(f);
  return *(ushort*)&h;
}

// async 16B global->LDS DMA. LDS dest = wave-uniform base + lane*16.
static __device__ __forceinline__ void cp16(const void* g, void* l) {
  __builtin_amdgcn_global_load_lds((const __attribute__((address_space(1))) void*)g,
                                   (__attribute__((address_space(3))) void*)l, 16, 0, 0);
}

// ---------------- builders ----------------

__global__ __launch_bounds__(256) void k_transpose_wq(const float* __restrict__ Wq,
                                                      ushort* __restrict__ WqT) {
  int u = blockIdx.x;
  for (int v = threadIdx.x; v < VV; v += blockDim.x)
    WqT[u * VV + v] = f2bf(Wq[(size_t)v * VV + u]);
}

__global__ __launch_bounds__(256) void k_build_pe(const float* __restrict__ h,
                                                  ushort* __restrict__ PE) {
  int t = blockIdx.x;
  ushort* out = PE + (size_t)t * TT;
  for (int p = threadIdx.x; p < TT; p += blockDim.x)
    out[p] = (p <= t) ? f2bf(h[t - p]) : (ushort)0;
}

__global__ __launch_bounds__(256) void k_build_etv(const int* __restrict__ idx,
                                                   const float* __restrict__ Wv,
                                                   ushort* __restrict__ ET,
                                                   ushort* __restrict__ VvT) {
  int bv = blockIdx.x;
  int b = bv >> 9, v = bv & (VV - 1);
  __shared__ float wrow[VV];
  for (int u = threadIdx.x; u < VV; u += blockDim.x) wrow[u] = Wv[(size_t)v * VV + u];
  __syncthreads();
  const int* row = idx + b * TT;
  ushort* oe = ET + (size_t)bv * TT;
  ushort* ov = VvT + (size_t)bv * TT;
  for (int s4 = threadIdx.x * 4; s4 < TT; s4 += blockDim.x * 4) {
    int4 iv = *(const int4*)(row + s4);
    ushort4 e, w;
    e.x = (iv.x == v) ? (ushort)0x3F80 : (ushort)0;  w.x = f2bf(wrow[iv.x]);
    e.y = (iv.y == v) ? (ushort)0x3F80 : (ushort)0;  w.y = f2bf(wrow[iv.y]);
    e.z = (iv.z == v) ? (ushort)0x3F80 : (ushort)0;  w.z = f2bf(wrow[iv.z]);
    e.w = (iv.w == v) ? (ushort)0x3F80 : (ushort)0;  w.w = f2bf(wrow[iv.w]);
    *(ushort4*)(oe + s4) = e;
    *(ushort4*)(ov + s4) = w;
  }
}

// ---------------- 128x128 MFMA GEMM core (verified R3 structure) ----------

#define GEMM_PRELUDE()                                                         \
  __shared__ __attribute__((aligned(16))) short As[128 * 32];                  \
  __shared__ __attribute__((aligned(16))) short Bs[128 * 32];                  \
  const int tid = threadIdx.x;                                                 \
  const int lane = tid & 63;                                                   \
  const int wm = (tid >> 6) & 1, wn = tid >> 7;                                \
  const int quad = lane >> 4, ln = lane & 15;                                  \
  const int rr = tid >> 2;                                                     \
  const int cg = (((tid & 3) ^ (rr & 3)) << 3);                                \
  short* a_dst = &As[tid * 8];                                                 \
  short* b_dst = &Bs[tid * 8];                                                 \
  const short* ap[4];                                                          \
  const short* bp[4];                                                          \
  _Pragma("unroll") for (int i = 0; i < 4; i++)                                \
      ap[i] = &As[(wm * 64 + i * 16 + ln) * 32 + ((quad ^ (ln & 3)) << 3)];    \
  _Pragma("unroll") for (int j = 0; j < 4; j++)                                \
      bp[j] = &Bs[(wn * 64 + j * 16 + ln) * 32 + ((quad ^ (ln & 3)) << 3)];

#define GEMM_KLOOP(NK)                                                         \
  _Pragma("unroll 1") for (int kt = 0; kt < (NK); ++kt) {                      \
    const int ko = kt << 5;                                                    \
    cp16(a_src0 + ko, a_dst);                                                  \
    cp16(a_src1 + ko, a_dst + 2048);                                           \
    cp16(b_src0 + ko, b_dst);                                                  \
    cp16(b_src1 + ko, b_dst + 2048);                                           \
    __syncthreads();                                                           \
    short8 af[4], bf[4];                                                       \
    _Pragma("unroll") for (int i = 0; i < 4; i++) af[i] = *(const short8*)ap[i]; \
    _Pragma("unroll") for (int j = 0; j < 4; j++) bf[j] = *(const short8*)bp[j]; \
    _Pragma("unroll") for (int i = 0; i < 4; i++)                              \
        _Pragma("unroll") for (int j = 0; j < 4; j++)                          \
            acc[i][j] =                                                        \
                __builtin_amdgcn_mfma_f32_16x16x32_bf16(af[i], bf[j], acc[i][j], 0, 0, 0); \
    __syncthreads();                                                           \
  }

#define ZERO_ACC()                                                             \
  _Pragma("unroll") for (int i = 0; i < 4; i++)                                \
      _Pragma("unroll") for (int j = 0; j < 4; j++)                            \
          acc[i][j] = (floatx4){0.f, 0.f, 0.f, 0.f};

// l1[b,t,v] = sum_p PE[t,p] * ET[b,v,p] — unpaired, heavy-t-first LPT order
__global__ __launch_bounds__(256) void k_gemm_l1(const ushort* __restrict__ PE,
                                                 const ushort* __restrict__ ET,
                                                 ushort* __restrict__ l1) {
  const int v_t = blockIdx.x, yy = blockIdx.y, b = blockIdx.z;
  const int t_t = (yy & 1) ? (7 - (yy >> 1)) : (15 - (yy >> 1));
  const int v0 = v_t << 7, t0 = t_t << 7;
  const int nk = (t_t << 2) + 4;
  GEMM_PRELUDE();
  const ushort* a_src0 = PE + (size_t)(t0 + rr) * TT + cg;
  const ushort* a_src1 = a_src0 + (size_t)64 * TT;
  const ushort* b_src0 = ET + ((size_t)((b << 9) + v0 + rr)) * TT + cg;
  const ushort* b_src1 = b_src0 + (size_t)64 * TT;
  floatx4 acc[4][4];
  ZERO_ACC();
  GEMM_KLOOP(nk);
#pragma unroll
  for (int i = 0; i < 4; i++)
#pragma unroll
    for (int j = 0; j < 4; j++) {
      const int rowb = t0 + wm * 64 + i * 16 + quad * 4;
      const int col = v0 + wn * 64 + j * 16 + ln;
#pragma unroll
      for (int r = 0; r < 4; r++)
        l1[((size_t)((b << 11) + rowb + r)) * VV + col] = f2bf(acc[i][j][r]);
    }
}

// Fused gemm1+gemm2: per (b, 64-row t-slab):
//   loop s-blocks of 128: P = tril(Q . l1^T)  (K=512, LDS-DMA staged)
//   P -> LDS (bf16, pitch 136), O += P . Vv  (Vv B-frags direct from L2)
__global__ __launch_bounds__(256, 2) void k_fused(const int* __restrict__ idx,
                                                  const ushort* __restrict__ WqT,
                                                  const ushort* __restrict__ l1,
                                                  const ushort* __restrict__ VvT,
                                                  float* __restrict__ out) {
  const int b = blockIdx.x;
  const int yy = blockIdx.y;
  const int t_t = (yy & 1) ? (15 - (yy >> 1)) : (31 - (yy >> 1));  // heavy first
  const int t0 = t_t << 6;
  const int nS = (t_t >> 1) + 1;  // s-blocks of 128 covering s <= t0+63

  __shared__ __attribute__((aligned(16))) short As[64 * 32];    // Q k-chunk
  __shared__ __attribute__((aligned(16))) short Bs[128 * 32];   // l1 k-chunk
  __shared__ __attribute__((aligned(16))) short Ps[64 * 136];   // P tile, padded

  const int tid = threadIdx.x;
  const int lane = tid & 63;
  const int w = tid >> 6;
  const int quad = lane >> 4, ln = lane & 15;
  const int wmA = w & 1, wnA = w >> 1;  // phase A: wave = 32t x 64s
  const int jw = w << 7;                // phase B: wave = 64t x 128j

  const int rr = tid >> 2;
  const int cg = (((tid & 3) ^ (rr & 3)) << 3);
  short* a_dst = &As[tid * 8];
  short* b_dst0 = &Bs[tid * 8];
  short* b_dst1 = &Bs[tid * 8 + 2048];

  const int u = idx[(b << 11) + t0 + rr];
  const ushort* a_src = WqT + (size_t)u * VV + cg;

  const short* apA[2];
  const short* bpA[4];
#pragma unroll
  for (int i = 0; i < 2; i++)
    apA[i] = &As[(wmA * 32 + i * 16 + ln) * 32 + ((quad ^ (ln & 3)) << 3)];
#pragma unroll
  for (int j = 0; j < 4; j++)
    bpA[j] = &Bs[(wnA * 64 + j * 16 + ln) * 32 + ((quad ^ (ln & 3)) << 3)];

  const ushort* vrow[8];
#pragma unroll
  for (int n = 0; n < 8; n++)
    vrow[n] = VvT + ((size_t)((b << 9) + jw + n * 16 + ln)) * TT + (quad << 3);

  const short* prow[4];
#pragma unroll
  for (int i = 0; i < 4; i++) prow[i] = &Ps[(i * 16 + ln) * 136 + (quad << 3)];

  floatx4 accO[4][8];
#pragma unroll
  for (int i = 0; i < 4; i++)
#pragma unroll
    for (int n = 0; n < 8; n++) accO[i][n] = (floatx4){0.f, 0.f, 0.f, 0.f};

#pragma unroll 1
  for (int s_t = 0; s_t < nS; ++s_t) {
    const int s0 = s_t << 7;
    // ---- phase A: P(64x128) = Q . l1^T over K=512 ----
    floatx4 accP[2][4];
#pragma unroll
    for (int i = 0; i < 2; i++)
#pragma unroll
      for (int j = 0; j < 4; j++) accP[i][j] = (floatx4){0.f, 0.f, 0.f, 0.f};
    const ushort* b_src = l1 + ((size_t)((b << 11) + s0 + rr)) * VV + cg;
#pragma unroll 1
    for (int kt = 0; kt < 16; ++kt) {
      const int ko = kt << 5;
      cp16(a_src + ko, a_dst);
      cp16(b_src + ko, b_dst0);
      cp16(b_src + (size_t)64 * VV + ko, b_dst1);
      __syncthreads();
      short8 af[2], bf[4];
#pragma unroll
      for (int i = 0; i < 2; i++) af[i] = *(const short8*)apA[i];
#pragma unroll
      for (int j = 0; j < 4; j++) bf[j] = *(const short8*)bpA[j];
#pragma unroll
      for (int i = 0; i < 2; i++)
#pragma unroll
        for (int j = 0; j < 4; j++)
          accP[i][j] =
              __builtin_amdgcn_mfma_f32_16x16x32_bf16(af[i], bf[j], accP[i][j], 0, 0, 0);
      __syncthreads();
    }
    // ---- write P to LDS (bf16), causal mask on the fly ----
#pragma unroll
    for (int i = 0; i < 2; i++)
#pragma unroll
      for (int j = 0; j < 4; j++) {
        const int pr = wmA * 32 + i * 16 + quad * 4;
        const int pc = wnA * 64 + j * 16 + ln;
#pragma unroll
        for (int r = 0; r < 4; r++) {
          float v = accP[i][j][r];
          if (s0 + pc > t0 + pr + r) v = 0.f;
          Ps[(pr + r) * 136 + pc] = (short)f2bf(v);
        }
      }
    __syncthreads();
    // ---- phase B: accO += P(64x128) . Vv — Vv frags direct from global ----
#pragma unroll 2
    for (int ks = 0; ks < 4; ++ks) {
      const int so = s0 + (ks << 5);
      short8 pf[4], vf[8];
#pragma unroll
      for (int n = 0; n < 8; n++) vf[n] = *(const short8*)(vrow[n] + so);
#pragma unroll
      for (int i = 0; i < 4; i++) pf[i] = *(const short8*)(prow[i] + (ks << 5));
#pragma unroll
      for (int i = 0; i < 4; i++)
#pragma unroll
        for (int n = 0; n < 8; n++)
          accO[i][n] =
              __builtin_amdgcn_mfma_f32_16x16x32_bf16(pf[i], vf[n], accO[i][n], 0, 0, 0);
    }
    __syncthreads();  // protect Ps before next s-iteration rewrites it
  }

  // ---- epilogue: O (64 x 512) fp32 ----
#pragma unroll
  for (int i = 0; i < 4; i++) {
    const int rowb = t0 + i * 16 + quad * 4;
#pragma unroll
    for (int n = 0; n < 8; n++) {
      const int col = jw + n * 16 + ln;
#pragma unroll
      for (int r = 0; r < 4; r++)
        out[((size_t)((b << 11) + rowb + r)) * VV + col] = accO[i][n][r];
    }
  }
}

extern "C" void kernel_launch(void* const* d_in, const int* in_sizes, int n_in,
                              void* d_out, int out_size, void* d_ws, size_t ws_size,
                              hipStream_t stream) {
  const int* idx = (const int*)d_in[0];
  const float* pos_table = (const float*)d_in[1];
  const float* Wq = (const float*)d_in[2];
  const float* Wv = (const float*)d_in[3];
  float* out = (float*)d_out;

  char* ws = (char*)d_ws;
  // ws layout (bytes):
  //   WqT bf16 (V,V)   :        0 ..    524288
  //   l1  bf16 (B,T,V) :   524288 ..  34078720
  //   VvT bf16 (B,V,T) : 34078720 ..  67633152
  //   PE  bf16 (T,T)   : 67633152 ..  76021760
  //   ET  bf16 (B,V,T) : 76021760 .. 109576192   (~105 MB total; a2 eliminated)
  ushort* WqT = (ushort*)(ws);
  ushort* l1 = (ushort*)(ws + 524288);
  ushort* VvT = (ushort*)(ws + 34078720UL);
  ushort* PE = (ushort*)(ws + 67633152UL);
  ushort* ET = (ushort*)(ws + 76021760UL);

  k_transpose_wq<<<dim3(VV), 256, 0, stream>>>(Wq, WqT);
  k_build_pe<<<dim3(TT), 256, 0, stream>>>(pos_table, PE);
  k_build_etv<<<dim3(BB * VV), 256, 0, stream>>>(idx, Wv, ET, VvT);
  k_gemm_l1<<<dim3(4, 16, BB), 256, 0, stream>>>(PE, ET, l1);
  k_fused<<<dim3(BB, 32), 256, 0, stream>>>(idx, WqT, l1, VvT, out);
}

// Round 5
// 331.589 us; speedup vs baseline: 1.1837x; 1.1837x over previous
//
#include <hip/hip_runtime.h>
#include <hip/hip_bf16.h>
#include <math.h>

#define BB 16
#define TT 2048
#define VV 512

typedef __attribute__((ext_vector_type(8))) short short8;
typedef __attribute__((ext_vector_type(4))) float floatx4;

static __device__ inline ushort f2bf(float f) {
  __hip_bfloat16 h = __float2bfloat16(f);
  return *(ushort*)&h;
}

// async 16B global->LDS DMA. LDS dest = wave-uniform base + lane*16.
static __device__ __forceinline__ void cp16(const void* g, void* l) {
  __builtin_amdgcn_global_load_lds((const __attribute__((address_space(1))) void*)g,
                                   (__attribute__((address_space(3))) void*)l, 16, 0, 0);
}

// ---------------- builders ----------------

__global__ __launch_bounds__(256) void k_transpose_wq(const float* __restrict__ Wq,
                                                      ushort* __restrict__ WqT) {
  int u = blockIdx.x;
  for (int v = threadIdx.x; v < VV; v += blockDim.x)
    WqT[u * VV + v] = f2bf(Wq[(size_t)v * VV + u]);
}

__global__ __launch_bounds__(256) void k_build_pe(const float* __restrict__ h,
                                                  ushort* __restrict__ PE) {
  int t = blockIdx.x;
  ushort* out = PE + (size_t)t * TT;
  for (int p = threadIdx.x; p < TT; p += blockDim.x)
    out[p] = (p <= t) ? f2bf(h[t - p]) : (ushort)0;
}

__global__ __launch_bounds__(256) void k_build_etv(const int* __restrict__ idx,
                                                   const float* __restrict__ Wv,
                                                   ushort* __restrict__ ET,
                                                   ushort* __restrict__ VvT) {
  int bv = blockIdx.x;
  int b = bv >> 9, v = bv & (VV - 1);
  __shared__ float wrow[VV];
  for (int u = threadIdx.x; u < VV; u += blockDim.x) wrow[u] = Wv[(size_t)v * VV + u];
  __syncthreads();
  const int* row = idx + b * TT;
  ushort* oe = ET + (size_t)bv * TT;
  ushort* ov = VvT + (size_t)bv * TT;
  for (int s4 = threadIdx.x * 4; s4 < TT; s4 += blockDim.x * 4) {
    int4 iv = *(const int4*)(row + s4);
    ushort4 e, w;
    e.x = (iv.x == v) ? (ushort)0x3F80 : (ushort)0;  w.x = f2bf(wrow[iv.x]);
    e.y = (iv.y == v) ? (ushort)0x3F80 : (ushort)0;  w.y = f2bf(wrow[iv.y]);
    e.z = (iv.z == v) ? (ushort)0x3F80 : (ushort)0;  w.z = f2bf(wrow[iv.z]);
    e.w = (iv.w == v) ? (ushort)0x3F80 : (ushort)0;  w.w = f2bf(wrow[iv.w]);
    *(ushort4*)(oe + s4) = e;
    *(ushort4*)(ov + s4) = w;
  }
}

// ---------------- 128x128 MFMA GEMM core (verified R3 structure) ----------

#define GEMM_PRELUDE()                                                         \
  __shared__ __attribute__((aligned(16))) short As[128 * 32];                  \
  __shared__ __attribute__((aligned(16))) short Bs[128 * 32];                  \
  const int tid = threadIdx.x;                                                 \
  const int lane = tid & 63;                                                   \
  const int wm = (tid >> 6) & 1, wn = tid >> 7;                                \
  const int quad = lane >> 4, ln = lane & 15;                                  \
  const int rr = tid >> 2;                                                     \
  const int cg = (((tid & 3) ^ (rr & 3)) << 3);                                \
  short* a_dst = &As[tid * 8];                                                 \
  short* b_dst = &Bs[tid * 8];                                                 \
  const short* ap[4];                                                          \
  const short* bp[4];                                                          \
  _Pragma("unroll") for (int i = 0; i < 4; i++)                                \
      ap[i] = &As[(wm * 64 + i * 16 + ln) * 32 + ((quad ^ (ln & 3)) << 3)];    \
  _Pragma("unroll") for (int j = 0; j < 4; j++)                                \
      bp[j] = &Bs[(wn * 64 + j * 16 + ln) * 32 + ((quad ^ (ln & 3)) << 3)];

#define GEMM_KLOOP(NK)                                                         \
  _Pragma("unroll 1") for (int kt = 0; kt < (NK); ++kt) {                      \
    const int ko = kt << 5;                                                    \
    cp16(a_src0 + ko, a_dst);                                                  \
    cp16(a_src1 + ko, a_dst + 2048);                                           \
    cp16(b_src0 + ko, b_dst);                                                  \
    cp16(b_src1 + ko, b_dst + 2048);                                           \
    __syncthreads();                                                           \
    short8 af[4], bf[4];                                                       \
    _Pragma("unroll") for (int i = 0; i < 4; i++) af[i] = *(const short8*)ap[i]; \
    _Pragma("unroll") for (int j = 0; j < 4; j++) bf[j] = *(const short8*)bp[j]; \
    _Pragma("unroll") for (int i = 0; i < 4; i++)                              \
        _Pragma("unroll") for (int j = 0; j < 4; j++)                          \
            acc[i][j] =                                                        \
                __builtin_amdgcn_mfma_f32_16x16x32_bf16(af[i], bf[j], acc[i][j], 0, 0, 0); \
    __syncthreads();                                                           \
  }

#define ZERO_ACC()                                                             \
  _Pragma("unroll") for (int i = 0; i < 4; i++)                                \
      _Pragma("unroll") for (int j = 0; j < 4; j++)                            \
          acc[i][j] = (floatx4){0.f, 0.f, 0.f, 0.f};

// l1[b,t,v] = sum_p PE[t,p] * ET[b,v,p] — unpaired, heavy-t-first LPT order
__global__ __launch_bounds__(256) void k_gemm_l1(const ushort* __restrict__ PE,
                                                 const ushort* __restrict__ ET,
                                                 ushort* __restrict__ l1) {
  const int v_t = blockIdx.x, yy = blockIdx.y, b = blockIdx.z;
  const int t_t = (yy & 1) ? (7 - (yy >> 1)) : (15 - (yy >> 1));
  const int v0 = v_t << 7, t0 = t_t << 7;
  const int nk = (t_t << 2) + 4;
  GEMM_PRELUDE();
  const ushort* a_src0 = PE + (size_t)(t0 + rr) * TT + cg;
  const ushort* a_src1 = a_src0 + (size_t)64 * TT;
  const ushort* b_src0 = ET + ((size_t)((b << 9) + v0 + rr)) * TT + cg;
  const ushort* b_src1 = b_src0 + (size_t)64 * TT;
  floatx4 acc[4][4];
  ZERO_ACC();
  GEMM_KLOOP(nk);
#pragma unroll
  for (int i = 0; i < 4; i++)
#pragma unroll
    for (int j = 0; j < 4; j++) {
      const int rowb = t0 + wm * 64 + i * 16 + quad * 4;
      const int col = v0 + wn * 64 + j * 16 + ln;
#pragma unroll
      for (int r = 0; r < 4; r++)
        l1[((size_t)((b << 11) + rowb + r)) * VV + col] = f2bf(acc[i][j][r]);
    }
}

// a2[b,t,s] = tril( WqT[idx[b,t]] . l1[b,s,:] ) — compact triangular grid
__global__ __launch_bounds__(256) void k_gemm1(const int* __restrict__ idx,
                                               const ushort* __restrict__ WqT,
                                               const ushort* __restrict__ l1,
                                               ushort* __restrict__ a2) {
  // decode linear tile id -> (t_t, s_t) in the lower triangle (136 tiles)
  const int lin = 135 - blockIdx.x;
  int t_t = (int)((sqrtf((float)(8 * lin + 1)) - 1.0f) * 0.5f);
  if ((t_t + 1) * (t_t + 2) / 2 <= lin) t_t++;
  else if (t_t * (t_t + 1) / 2 > lin) t_t--;
  const int s_t = lin - t_t * (t_t + 1) / 2;
  const int b = blockIdx.y;
  const int t0 = t_t << 7, s0 = s_t << 7;
  GEMM_PRELUDE();
  const int u0 = idx[(b << 11) + t0 + rr];
  const int u1 = idx[(b << 11) + t0 + rr + 64];
  const ushort* a_src0 = WqT + (size_t)u0 * VV + cg;
  const ushort* a_src1 = WqT + (size_t)u1 * VV + cg;
  const ushort* b_src0 = l1 + ((size_t)((b << 11) + s0 + rr)) * VV + cg;
  const ushort* b_src1 = b_src0 + (size_t)64 * VV;
  floatx4 acc[4][4];
  ZERO_ACC();
  GEMM_KLOOP(16);
#pragma unroll
  for (int i = 0; i < 4; i++)
#pragma unroll
    for (int j = 0; j < 4; j++) {
      const int rowb = t0 + wm * 64 + i * 16 + quad * 4;
      const int col = s0 + wn * 64 + j * 16 + ln;
#pragma unroll
      for (int r = 0; r < 4; r++) {
        const int row = rowb + r;
        float v = acc[i][j][r];
        if (col > row) v = 0.f;
        a2[((size_t)((b << 11) + row)) * TT + col] = f2bf(v);
      }
    }
}

// logits[b,t,j] = sum_s a2[b,t,s] * VvT[b,j,s] — unpaired, t descending
__global__ __launch_bounds__(256) void k_gemm2(const ushort* __restrict__ a2,
                                               const ushort* __restrict__ VvT,
                                               float* __restrict__ out) {
  const int j_t = blockIdx.x, b = blockIdx.z;
  const int t_t = 15 - blockIdx.y;  // heavy tiles first
  const int t0 = t_t << 7, j0 = j_t << 7;
  const int nk = (t_t << 2) + 4;
  GEMM_PRELUDE();
  const ushort* a_src0 = a2 + ((size_t)((b << 11) + t0 + rr)) * TT + cg;
  const ushort* a_src1 = a_src0 + (size_t)64 * TT;
  const ushort* b_src0 = VvT + ((size_t)((b << 9) + j0 + rr)) * TT + cg;
  const ushort* b_src1 = b_src0 + (size_t)64 * TT;
  floatx4 acc[4][4];
  ZERO_ACC();
  GEMM_KLOOP(nk);
#pragma unroll
  for (int i = 0; i < 4; i++)
#pragma unroll
    for (int j = 0; j < 4; j++) {
      const int rowb = t0 + wm * 64 + i * 16 + quad * 4;
      const int col = j0 + wn * 64 + j * 16 + ln;
#pragma unroll
      for (int r = 0; r < 4; r++)
        out[((size_t)((b << 11) + rowb + r)) * VV + col] = acc[i][j][r];
    }
}

extern "C" void kernel_launch(void* const* d_in, const int* in_sizes, int n_in,
                              void* d_out, int out_size, void* d_ws, size_t ws_size,
                              hipStream_t stream) {
  const int* idx = (const int*)d_in[0];
  const float* pos_table = (const float*)d_in[1];
  const float* Wq = (const float*)d_in[2];
  const float* Wv = (const float*)d_in[3];
  float* out = (float*)d_out;

  char* ws = (char*)d_ws;
  // ws layout (bytes):
  //   WqT bf16 (V,V)   :        0 ..    524288
  //   l1  bf16 (B,T,V) :   524288 ..  34078720
  //   VvT bf16 (B,V,T) : 34078720 ..  67633152
  //   a2  bf16 (B,T,T) : 67633152 .. 201850880
  //   PE  bf16 (T,T)   : aliases a2[0..8MB]    (dead before a2 written)
  //   ET  bf16 (B,V,T) : aliases a2[8..40MB]   (dead before a2 written)
  ushort* WqT = (ushort*)(ws);
  ushort* l1 = (ushort*)(ws + 524288);
  ushort* VvT = (ushort*)(ws + 34078720UL);
  ushort* a2 = (ushort*)(ws + 67633152UL);
  ushort* PE = (ushort*)(ws + 67633152UL);
  ushort* ET = (ushort*)(ws + 67633152UL + 8388608UL);

  k_transpose_wq<<<dim3(VV), 256, 0, stream>>>(Wq, WqT);
  k_build_pe<<<dim3(TT), 256, 0, stream>>>(pos_table, PE);
  k_build_etv<<<dim3(BB * VV), 256, 0, stream>>>(idx, Wv, ET, VvT);
  k_gemm_l1<<<dim3(4, 16, BB), 256, 0, stream>>>(PE, ET, l1);
  k_gemm1<<<dim3(136, BB), 256, 0, stream>>>(idx, WqT, l1, a2);
  k_gemm2<<<dim3(4, 16, BB), 256, 0, stream>>>(a2, VvT, out);
}

// Round 6
// 297.063 us; speedup vs baseline: 1.3212x; 1.1162x over previous
//
#include <hip/hip_runtime.h>
#include <hip/hip_bf16.h>
#include <math.h>

#define BB 16
#define TT 2048
#define VV 512

typedef __attribute__((ext_vector_type(8))) short short8;
typedef __attribute__((ext_vector_type(4))) float floatx4;

static __device__ inline ushort f2bf(float f) {
  __hip_bfloat16 h = __float2bfloat16(f);
  return *(ushort*)&h;
}

// async 16B global->LDS DMA. LDS dest = wave-uniform base + lane*16.
static __device__ __forceinline__ void cp16(const void* g, void* l) {
  __builtin_amdgcn_global_load_lds((const __attribute__((address_space(1))) void*)g,
                                   (__attribute__((address_space(3))) void*)l, 16, 0, 0);
}

// Static-balance tile mapping: dispatcher assigns blocks round-robin mod 256,
// so a CU's co-resident set = ids {c, c+256, c+512, c+768} = same (x, y, z&3),
// q = z>>2 in {0,1,2,3}. Choose t from {r, r+8, 7-r, 15-r} (r = y&3): every
// co-set's total K-work = 4*(r + r+8 + 7-r + 15-r)/4... sum nk = 136 exactly.
static __device__ __forceinline__ void balance_map(int y, int z, int* t_t, int* b) {
  const int r = y & 3, q = z >> 2;
  int t = (q == 0) ? r : (q == 1) ? (r + 8) : (q == 2) ? (7 - r) : (15 - r);
  *t_t = t;
  *b = ((z & 3) << 2) | (y >> 2);
}

// ---------------- builders ----------------

__global__ __launch_bounds__(256) void k_transpose_wq(const float* __restrict__ Wq,
                                                      ushort* __restrict__ WqT) {
  int u = blockIdx.x;
  for (int v = threadIdx.x; v < VV; v += blockDim.x)
    WqT[u * VV + v] = f2bf(Wq[(size_t)v * VV + u]);
}

__global__ __launch_bounds__(256) void k_build_pe(const float* __restrict__ h,
                                                  ushort* __restrict__ PE) {
  int t = blockIdx.x;
  ushort* out = PE + (size_t)t * TT;
  for (int p = threadIdx.x; p < TT; p += blockDim.x)
    out[p] = (p <= t) ? f2bf(h[t - p]) : (ushort)0;
}

__global__ __launch_bounds__(256) void k_build_etv(const int* __restrict__ idx,
                                                   const float* __restrict__ Wv,
                                                   ushort* __restrict__ ET,
                                                   ushort* __restrict__ VvT) {
  int bv = blockIdx.x;
  int b = bv >> 9, v = bv & (VV - 1);
  __shared__ float wrow[VV];
  for (int u = threadIdx.x; u < VV; u += blockDim.x) wrow[u] = Wv[(size_t)v * VV + u];
  __syncthreads();
  const int* row = idx + b * TT;
  ushort* oe = ET + (size_t)bv * TT;
  ushort* ov = VvT + (size_t)bv * TT;
  for (int s4 = threadIdx.x * 4; s4 < TT; s4 += blockDim.x * 4) {
    int4 iv = *(const int4*)(row + s4);
    ushort4 e, w;
    e.x = (iv.x == v) ? (ushort)0x3F80 : (ushort)0;  w.x = f2bf(wrow[iv.x]);
    e.y = (iv.y == v) ? (ushort)0x3F80 : (ushort)0;  w.y = f2bf(wrow[iv.y]);
    e.z = (iv.z == v) ? (ushort)0x3F80 : (ushort)0;  w.z = f2bf(wrow[iv.z]);
    e.w = (iv.w == v) ? (ushort)0x3F80 : (ushort)0;  w.w = f2bf(wrow[iv.w]);
    *(ushort4*)(oe + s4) = e;
    *(ushort4*)(ov + s4) = w;
  }
}

// ---------------- 128x128 MFMA GEMM core ----------

#define GEMM_PRELUDE()                                                         \
  __shared__ __attribute__((aligned(16))) short As[128 * 32];                  \
  __shared__ __attribute__((aligned(16))) short Bs[128 * 32];                  \
  const int tid = threadIdx.x;                                                 \
  const int lane = tid & 63;                                                   \
  const int wm = (tid >> 6) & 1, wn = tid >> 7;                                \
  const int quad = lane >> 4, ln = lane & 15;                                  \
  const int rr = tid >> 2;                                                     \
  const int cg = (((tid & 3) ^ (rr & 3)) << 3);                                \
  short* a_dst = &As[tid * 8];                                                 \
  short* b_dst = &Bs[tid * 8];                                                 \
  const short* ap[4];                                                          \
  const short* bp[4];                                                          \
  _Pragma("unroll") for (int i = 0; i < 4; i++)                                \
      ap[i] = &As[(wm * 64 + i * 16 + ln) * 32 + ((quad ^ (ln & 3)) << 3)];    \
  _Pragma("unroll") for (int j = 0; j < 4; j++)                                \
      bp[j] = &Bs[(wn * 64 + j * 16 + ln) * 32 + ((quad ^ (ln & 3)) << 3)];

#define GEMM_KLOOP(NK)                                                         \
  _Pragma("unroll 1") for (int kt = 0; kt < (NK); ++kt) {                      \
    const int ko = kt << 5;                                                    \
    cp16(a_src0 + ko, a_dst);                                                  \
    cp16(a_src1 + ko, a_dst + 2048);                                           \
    cp16(b_src0 + ko, b_dst);                                                  \
    cp16(b_src1 + ko, b_dst + 2048);                                           \
    __syncthreads();                                                           \
    short8 af[4], bf[4];                                                       \
    _Pragma("unroll") for (int i = 0; i < 4; i++) af[i] = *(const short8*)ap[i]; \
    _Pragma("unroll") for (int j = 0; j < 4; j++) bf[j] = *(const short8*)bp[j]; \
    _Pragma("unroll") for (int i = 0; i < 4; i++)                              \
        _Pragma("unroll") for (int j = 0; j < 4; j++)                          \
            acc[i][j] =                                                        \
                __builtin_amdgcn_mfma_f32_16x16x32_bf16(af[i], bf[j], acc[i][j], 0, 0, 0); \
    __syncthreads();                                                           \
  }

#define ZERO_ACC()                                                             \
  _Pragma("unroll") for (int i = 0; i < 4; i++)                                \
      _Pragma("unroll") for (int j = 0; j < 4; j++)                            \
          acc[i][j] = (floatx4){0.f, 0.f, 0.f, 0.f};

// l1[b,t,v] = sum_p PE[t,p] * ET[b,v,p] — static-balanced (t,b) mapping
__global__ __launch_bounds__(256) void k_gemm_l1(const ushort* __restrict__ PE,
                                                 const ushort* __restrict__ ET,
                                                 ushort* __restrict__ l1) {
  int t_t, b;
  balance_map(blockIdx.y, blockIdx.z, &t_t, &b);
  const int v_t = blockIdx.x;
  const int v0 = v_t << 7, t0 = t_t << 7;
  const int nk = (t_t << 2) + 4;
  GEMM_PRELUDE();
  const ushort* a_src0 = PE + (size_t)(t0 + rr) * TT + cg;
  const ushort* a_src1 = a_src0 + (size_t)64 * TT;
  const ushort* b_src0 = ET + ((size_t)((b << 9) + v0 + rr)) * TT + cg;
  const ushort* b_src1 = b_src0 + (size_t)64 * TT;
  floatx4 acc[4][4];
  ZERO_ACC();
  GEMM_KLOOP(nk);
#pragma unroll
  for (int i = 0; i < 4; i++)
#pragma unroll
    for (int j = 0; j < 4; j++) {
      const int rowb = t0 + wm * 64 + i * 16 + quad * 4;
      const int col = v0 + wn * 64 + j * 16 + ln;
#pragma unroll
      for (int r = 0; r < 4; r++)
        l1[((size_t)((b << 11) + rowb + r)) * VV + col] = f2bf(acc[i][j][r]);
    }
}

// a2[b,t,s] = tril( WqT[idx[b,t]] . l1[b,s,:] ) — compact triangular grid
__global__ __launch_bounds__(256) void k_gemm1(const int* __restrict__ idx,
                                               const ushort* __restrict__ WqT,
                                               const ushort* __restrict__ l1,
                                               ushort* __restrict__ a2) {
  const int lin = 135 - blockIdx.x;
  int t_t = (int)((sqrtf((float)(8 * lin + 1)) - 1.0f) * 0.5f);
  if ((t_t + 1) * (t_t + 2) / 2 <= lin) t_t++;
  else if (t_t * (t_t + 1) / 2 > lin) t_t--;
  const int s_t = lin - t_t * (t_t + 1) / 2;
  const int b = blockIdx.y;
  const int t0 = t_t << 7, s0 = s_t << 7;
  GEMM_PRELUDE();
  const int u0 = idx[(b << 11) + t0 + rr];
  const int u1 = idx[(b << 11) + t0 + rr + 64];
  const ushort* a_src0 = WqT + (size_t)u0 * VV + cg;
  const ushort* a_src1 = WqT + (size_t)u1 * VV + cg;
  const ushort* b_src0 = l1 + ((size_t)((b << 11) + s0 + rr)) * VV + cg;
  const ushort* b_src1 = b_src0 + (size_t)64 * VV;
  floatx4 acc[4][4];
  ZERO_ACC();
  GEMM_KLOOP(16);
#pragma unroll
  for (int i = 0; i < 4; i++)
#pragma unroll
    for (int j = 0; j < 4; j++) {
      const int rowb = t0 + wm * 64 + i * 16 + quad * 4;
      const int col = s0 + wn * 64 + j * 16 + ln;
#pragma unroll
      for (int r = 0; r < 4; r++) {
        const int row = rowb + r;
        float v = acc[i][j][r];
        if (col > row) v = 0.f;
        a2[((size_t)((b << 11) + row)) * TT + col] = f2bf(v);
      }
    }
}

// logits[b,t,j] = sum_s a2[b,t,s] * VvT[b,j,s] — static-balanced (t,b) mapping
__global__ __launch_bounds__(256) void k_gemm2(const ushort* __restrict__ a2,
                                               const ushort* __restrict__ VvT,
                                               float* __restrict__ out) {
  int t_t, b;
  balance_map(blockIdx.y, blockIdx.z, &t_t, &b);
  const int j_t = blockIdx.x;
  const int t0 = t_t << 7, j0 = j_t << 7;
  const int nk = (t_t << 2) + 4;
  GEMM_PRELUDE();
  const ushort* a_src0 = a2 + ((size_t)((b << 11) + t0 + rr)) * TT + cg;
  const ushort* a_src1 = a_src0 + (size_t)64 * TT;
  const ushort* b_src0 = VvT + ((size_t)((b << 9) + j0 + rr)) * TT + cg;
  const ushort* b_src1 = b_src0 + (size_t)64 * TT;
  floatx4 acc[4][4];
  ZERO_ACC();
  GEMM_KLOOP(nk);
#pragma unroll
  for (int i = 0; i < 4; i++)
#pragma unroll
    for (int j = 0; j < 4; j++) {
      const int rowb = t0 + wm * 64 + i * 16 + quad * 4;
      const int col = j0 + wn * 64 + j * 16 + ln;
#pragma unroll
      for (int r = 0; r < 4; r++)
        out[((size_t)((b << 11) + rowb + r)) * VV + col] = acc[i][j][r];
    }
}

extern "C" void kernel_launch(void* const* d_in, const int* in_sizes, int n_in,
                              void* d_out, int out_size, void* d_ws, size_t ws_size,
                              hipStream_t stream) {
  const int* idx = (const int*)d_in[0];
  const float* pos_table = (const float*)d_in[1];
  const float* Wq = (const float*)d_in[2];
  const float* Wv = (const float*)d_in[3];
  float* out = (float*)d_out;

  char* ws = (char*)d_ws;
  // ws layout (bytes):
  //   WqT bf16 (V,V)   :        0 ..    524288
  //   l1  bf16 (B,T,V) :   524288 ..  34078720
  //   VvT bf16 (B,V,T) : 34078720 ..  67633152
  //   a2  bf16 (B,T,T) : 67633152 .. 201850880
  //   PE  bf16 (T,T)   : aliases a2[0..8MB]    (dead before a2 written)
  //   ET  bf16 (B,V,T) : aliases a2[8..40MB]   (dead before a2 written)
  ushort* WqT = (ushort*)(ws);
  ushort* l1 = (ushort*)(ws + 524288);
  ushort* VvT = (ushort*)(ws + 34078720UL);
  ushort* a2 = (ushort*)(ws + 67633152UL);
  ushort* PE = (ushort*)(ws + 67633152UL);
  ushort* ET = (ushort*)(ws + 67633152UL + 8388608UL);

  k_transpose_wq<<<dim3(VV), 256, 0, stream>>>(Wq, WqT);
  k_build_pe<<<dim3(TT), 256, 0, stream>>>(pos_table, PE);
  k_build_etv<<<dim3(BB * VV), 256, 0, stream>>>(idx, Wv, ET, VvT);
  k_gemm_l1<<<dim3(4, 16, BB), 256, 0, stream>>>(PE, ET, l1);
  k_gemm1<<<dim3(136, BB), 256, 0, stream>>>(idx, WqT, l1, a2);
  k_gemm2<<<dim3(4, 16, BB), 256, 0, stream>>>(a2, VvT, out);
}